// Round 15
// baseline (36.397 us; speedup 1.0000x reference)
//
#include <hip/hip_runtime.h>
#include <hip/hip_bf16.h>

// B=8, N=64, P=128, DNODE=2048, DEDGE=1024, DEMB=512, E=32768
// lookup(b,i,j)=b*4096+i*64+j; only 2048 of 32768 edge rows used; (e1+e2)*0.5
// folds into the gathered GEMM input (linearity).
// Budget (R13-R14 subtraction): gemm=14.0us, prep~6, epilogue+gaps~14.
// This round: k_gemm inner loop -> global_load_lds (no reg round-trip, no
// ds_write), 3-buffer 2-ahead pipeline, counted vmcnt(2)+s_barrier fused in
// one asm (never drain mid-loop), T2 XOR swizzle on BOTH sides (pre-swizzled
// global source chunk, swizzled fragment-read address; LDS linear).

typedef _Float16 h16;
typedef h16 h16x4 __attribute__((ext_vector_type(4)));
typedef h16 h16x8 __attribute__((ext_vector_type(8)));
typedef float f32x4 __attribute__((ext_vector_type(4)));

// ---------------- ws layout (bytes) ----------------
static const long O_W3T  = 0;         // 1536*2048*2 (phi|psi|node K-major)
static const long O_WREL = 6291456;   // 512*1024*2
static const long O_XH   = 7340032;   // 512*2048*2
static const long O_G    = 9437184;   // 1024*1024*2 (0.5*(f_fwd+f_rev) f16)
static const long O_B3   = 11534336;  // 1536*4
static const long O_YH   = 11540480;  // 512*1536*2 (phi|psi|node f16)

__global__ __launch_bounds__(256) void k_prep(
    const float* __restrict__ Wphi, const float* __restrict__ Wpsi,
    const float* __restrict__ Wnode, const float* __restrict__ Wrel,
    const float* __restrict__ x, const float* __restrict__ bphi,
    const float* __restrict__ bpsi, const float* __restrict__ bnode,
    const float* __restrict__ feat, const int* __restrict__ pairs,
    h16* __restrict__ W3t, h16* __restrict__ Wrelt, h16* __restrict__ xh,
    float* __restrict__ b3, h16* __restrict__ G) {
  __shared__ float t[32][33];
  int bid = blockIdx.x, tid = threadIdx.x;
  if (bid < 3584) {
    const float* src; h16* dst; int K, tk, tn;
    if (bid < 3072) {
      int mat = bid >> 10, rem = bid & 1023;
      tk = rem >> 4; tn = rem & 15;
      src = mat == 0 ? Wphi : (mat == 1 ? Wpsi : Wnode);
      K = 2048; dst = W3t + (long)mat * 512 * 2048;
    } else {
      int rem = bid - 3072;
      tk = rem >> 4; tn = rem & 15;
      src = Wrel; K = 1024; dst = Wrelt;
    }
    {
      int row = tid >> 3, c4 = (tid & 7) * 4;
      float4 v = *(const float4*)(src + (long)(tk*32 + row)*512 + tn*32 + c4);
      t[row][c4+0] = v.x; t[row][c4+1] = v.y; t[row][c4+2] = v.z; t[row][c4+3] = v.w;
    }
    __syncthreads();
    {
      int n = tid >> 3, k4 = (tid & 7) * 4;
      h16x4 o = { (h16)t[k4+0][n], (h16)t[k4+1][n], (h16)t[k4+2][n], (h16)t[k4+3][n] };
      *(h16x4*)(dst + (long)(tn*32 + n)*K + tk*32 + k4) = o;
    }
  } else if (bid < 4102) {
    int b2 = bid - 3584;
    if (b2 < 512) {
      int idx = (b2*256 + tid) * 8;
      const float4* xv = (const float4*)(x + idx);
      float4 v0 = xv[0], v1 = xv[1];
      h16x8 o;
      o[0]=(h16)v0.x; o[1]=(h16)v0.y; o[2]=(h16)v0.z; o[3]=(h16)v0.w;
      o[4]=(h16)v1.x; o[5]=(h16)v1.y; o[6]=(h16)v1.z; o[7]=(h16)v1.w;
      *(h16x8*)(xh + idx) = o;
    } else {
      int i = (b2 - 512)*256 + tid;
      if (i < 1536) b3[i] = i < 512 ? bphi[i] : (i < 1024 ? bpsi[i-512] : bnode[i-1024]);
    }
  } else {
    int r = bid - 4102;
    int b = r >> 7;
    int i0 = pairs[r*2], i1 = pairs[r*2+1];
    const float4* f0 = (const float4*)(feat + (long)((b*64 + i0)*64 + i1) * 1024);
    const float4* f1 = (const float4*)(feat + (long)((b*64 + i1)*64 + i0) * 1024);
    float4 a = f0[tid], c = f1[tid];
    h16x4 o;
    o[0]=(h16)(0.5f*(a.x+c.x)); o[1]=(h16)(0.5f*(a.y+c.y));
    o[2]=(h16)(0.5f*(a.z+c.z)); o[3]=(h16)(0.5f*(a.w+c.w));
    *(h16x4*)(G + (long)r*1024 + tid*4) = o;
  }
}

// 4-wave 32x32 compute (verified) — epilogue scores GEMM.
__device__ __forceinline__ void mfma_compute(
    const h16 (*__restrict__ As)[72], const h16 (*__restrict__ Bs)[72],
    int wm, int wn, int fr, int kg, f32x4 acc[2][2]) {
#pragma unroll
  for (int kc = 0; kc < 2; ++kc) {
    int kb = kc*32 + kg;
    h16x8 fa0 = *(const h16x8*)&As[wm*32 + fr][kb];
    h16x8 fa1 = *(const h16x8*)&As[wm*32 + 16 + fr][kb];
    h16x8 fb0 = *(const h16x8*)&Bs[wn*32 + fr][kb];
    h16x8 fb1 = *(const h16x8*)&Bs[wn*32 + 16 + fr][kb];
    acc[0][0] = __builtin_amdgcn_mfma_f32_16x16x32_f16(fa0, fb0, acc[0][0], 0,0,0);
    acc[0][1] = __builtin_amdgcn_mfma_f32_16x16x32_f16(fa0, fb1, acc[0][1], 0,0,0);
    acc[1][0] = __builtin_amdgcn_mfma_f32_16x16x32_f16(fa1, fb0, acc[1][0], 0,0,0);
    acc[1][1] = __builtin_amdgcn_mfma_f32_16x16x32_f16(fa1, fb1, acc[1][1], 0,0,0);
  }
}

// ---- k_gemm tile loop: global_load_lds + XOR swizzle + counted vmcnt ----
// Staging: thread (tid) covers row rw=tid>>3, source chunk cs=(tid&7)^(rw&7);
// HW writes lane-linear -> LDS[row][chunk c] holds global chunk c^(row&7).
// Read: global chunk g of row r lives at LDS slot g^(r&7).
template<int S>
__device__ __forceinline__ void gemm_tile(
    const h16* Ag, const h16* Bg,
    h16 (*Ab3)[64][64], h16 (*Bb3)[64][64],
    int w8, int baseA0, int baseA1, int baseB, int m7, int ch0,
    f32x4 acc[2]) {
#define STG(t_, b_) do {                                                      \
    __builtin_amdgcn_global_load_lds(                                         \
        (const __attribute__((address_space(1))) unsigned int*)(Ag + (t_)*64),\
        (__attribute__((address_space(3))) unsigned int*)&Ab3[b_][w8][0],     \
        16, 0, 0);                                                            \
    __builtin_amdgcn_global_load_lds(                                         \
        (const __attribute__((address_space(1))) unsigned int*)(Bg + (t_)*64),\
        (__attribute__((address_space(3))) unsigned int*)&Bb3[b_][w8][0],     \
        16, 0, 0); } while (0)

  STG(0, 0);
  STG(1, 1);
  asm volatile("s_waitcnt vmcnt(2)\n\ts_barrier" ::: "memory");
#pragma unroll
  for (int t = 0; t < S; ++t) {
    const int cur = t % 3, nb = (t + 2) % 3;
    if (t + 2 < S) STG(t + 2, nb);
    const char* Ac = (const char*)Ab3[cur];
    const char* Bc = (const char*)Bb3[cur];
#pragma unroll
    for (int kc = 0; kc < 2; ++kc) {
      int sw = ((kc*4 + ch0) ^ m7) << 4;
      h16x8 fa0 = *(const h16x8*)(Ac + baseA0 + sw);
      h16x8 fa1 = *(const h16x8*)(Ac + baseA1 + sw);
      h16x8 fb  = *(const h16x8*)(Bc + baseB  + sw);
      acc[0] = __builtin_amdgcn_mfma_f32_16x16x32_f16(fa0, fb, acc[0], 0,0,0);
      acc[1] = __builtin_amdgcn_mfma_f32_16x16x32_f16(fa1, fb, acc[1], 0,0,0);
    }
    if (t + 1 < S) {
      if (t + 2 < S) asm volatile("s_waitcnt vmcnt(2)\n\ts_barrier" ::: "memory");
      else           asm volatile("s_waitcnt vmcnt(0)\n\ts_barrier" ::: "memory");
    }
  }
#undef STG
}

// 256 blocks x 512 threads (8 waves: 2M x 4N, each 32x16 out).
__global__ __launch_bounds__(512) void k_gemm(
    const h16* __restrict__ xh, const h16* __restrict__ W3t,
    const float* __restrict__ b3, h16* __restrict__ Yh,
    const h16* __restrict__ G, const h16* __restrict__ Wrelt,
    const float* __restrict__ brel, float* __restrict__ out) {
  __shared__ __align__(16) h16 Ab3[3][64][64];
  __shared__ __align__(16) h16 Bb3[3][64][64];
  int bid = blockIdx.x, tid = threadIdx.x;
  int lane = tid & 63, wave = tid >> 6;
  int wm = wave >> 2, wn = wave & 3;
  int fr = lane & 15, ch0 = lane >> 4, m7 = fr & 7;
  int rw = tid >> 3;                      // staging row 0..63
  int cs = (tid & 7) ^ (rw & 7);          // pre-swizzled source chunk
  int w8 = wave * 8;
  int baseA0 = (wm*32 + fr) * 128;
  int baseA1 = (wm*32 + 16 + fr) * 128;
  int baseB  = (wn*16 + fr) * 128;
  int r0 = 4 * (lane >> 4);

  if (bid < 192) {               // Yh(512x1536) = xh @ W3t^T + b3
    int tileM = (bid / 24) * 64, tileN = (bid % 24) * 64;
    const h16* Ag = xh  + (long)(tileM + rw) * 2048 + cs * 8;
    const h16* Bg = W3t + (long)(tileN + rw) * 2048 + cs * 8;
    f32x4 acc[2] = {};
    gemm_tile<32>(Ag, Bg, Ab3, Bb3, w8, baseA0, baseA1, baseB, m7, ch0, acc);
    int col = tileN + wn*16 + fr;
    float bb = b3[col];
#pragma unroll
    for (int m = 0; m < 2; ++m) {
      int row = tileM + wm*32 + m*16 + r0;
#pragma unroll
      for (int r = 0; r < 4; ++r)
        Yh[(long)(row + r) * 1536 + col] = (h16)(acc[m][r] + bb);
    }
  } else {                       // edge(1024x512) = G @ Wrelt^T + brel
#pragma unroll 1
    for (int ti = 0; ti < 2; ++ti) {
      if (ti) __syncthreads();   // full drain between tiles (stores + stale bufs)
      int e = (bid - 192) * 2 + ti;           // 128 tiles
      int tileM = (e >> 3) * 64, tileN = (e & 7) * 64;
      const h16* Ag = G     + (long)(tileM + rw) * 1024 + cs * 8;
      const h16* Bg = Wrelt + (long)(tileN + rw) * 1024 + cs * 8;
      f32x4 acc[2] = {};
      gemm_tile<16>(Ag, Bg, Ab3, Bb3, w8, baseA0, baseA1, baseB, m7, ch0, acc);
      int col = tileN + wn*16 + fr;
      float bb = brel[col];
#pragma unroll
      for (int m = 0; m < 2; ++m) {
        int row = tileM + wm*32 + m*16 + r0;
#pragma unroll
        for (int r = 0; r < 4; ++r)
          out[32768 + 512 + (long)(row + r) * 1024 + col] = acc[m][r] + bb;
      }
    }
  }
}

// Epilogue scores pipeline (verified R3 path).
#define GEMM_PIPELINE(Agp, Bgp, K)                                        \
  {                                                                       \
    h16x8 ra0 = *(const h16x8*)(Agp);                                     \
    h16x8 ra1 = *(const h16x8*)(Agp + 8);                                 \
    h16x8 rb0 = *(const h16x8*)(Bgp);                                     \
    h16x8 rb1 = *(const h16x8*)(Bgp + 8);                                 \
    *(h16x8*)&As[0][srow][skp]   = ra0;                                   \
    *(h16x8*)&As[0][srow][skp+8] = ra1;                                   \
    *(h16x8*)&Bs[0][srow][skp]   = rb0;                                   \
    *(h16x8*)&Bs[0][srow][skp+8] = rb1;                                   \
    __syncthreads();                                                      \
    int cur = 0;                                                          \
    for (int k0 = 64; k0 < (K); k0 += 64) {                               \
      ra0 = *(const h16x8*)(Agp + k0);                                    \
      ra1 = *(const h16x8*)(Agp + k0 + 8);                                \
      rb0 = *(const h16x8*)(Bgp + k0);                                    \
      rb1 = *(const h16x8*)(Bgp + k0 + 8);                                \
      mfma_compute(As[cur], Bs[cur], wm, wn, fr, kg, acc);                \
      int nxt = cur ^ 1;                                                  \
      *(h16x8*)&As[nxt][srow][skp]   = ra0;                               \
      *(h16x8*)&As[nxt][srow][skp+8] = ra1;                               \
      *(h16x8*)&Bs[nxt][srow][skp]   = rb0;                               \
      *(h16x8*)&Bs[nxt][srow][skp+8] = rb1;                               \
      __syncthreads();                                                    \
      cur = nxt;                                                          \
    }                                                                     \
    mfma_compute(As[cur], Bs[cur], wm, wn, fr, kg, acc);                  \
  }

__global__ __launch_bounds__(256) void k_epilogue(
    const h16* __restrict__ Yh, const int* __restrict__ pairs,
    float* __restrict__ out) {
  __shared__ __align__(16) h16 As[2][64][72];
  __shared__ __align__(16) h16 Bs[2][64][72];
  int bid = blockIdx.x, tid = threadIdx.x;
  if (bid < 8) {
    int lane = tid & 63, wave = tid >> 6;
    int wm = wave >> 1, wn = wave & 1;
    int srow = tid >> 2, skp = (tid & 3) * 16;
    int fr = lane & 15, kg = (lane >> 4) * 8;
    const h16* Ab = Yh + (long)bid * 64 * 1536;
    const h16* Agp = Ab + (long)srow * 1536 + skp;
    const h16* Bgp = Ab + (long)srow * 1536 + 512 + skp;
    f32x4 acc[2][2] = {};
    GEMM_PIPELINE(Agp, Bgp, 512);
    int r0 = 4 * (lane >> 4), c0 = lane & 15;
    float* ob = out + (long)bid * 4096;
#pragma unroll
    for (int m = 0; m < 2; ++m)
#pragma unroll
      for (int n = 0; n < 2; ++n) {
        int row = wm*32 + m*16 + r0;
        int col = wn*32 + n*16 + c0;
#pragma unroll
        for (int r = 0; r < 4; ++r) {
          float s = acc[m][n][r];
          ob[(long)(row + r) * 64 + col] = 1.f / (1.f + expf(-s));
        }
      }
  } else {
    int r = bid - 8;
    int b = r >> 7;
    int i0 = pairs[r*2], i1 = pairs[r*2+1];
    const h16* n0 = Yh + (long)(b*64 + i0)*1536 + 1024;
    const h16* n1 = Yh + (long)(b*64 + i1)*1536 + 1024;
    float* o = out + 32768 + (long)r*1024;
    for (int c = tid; c < 512; c += 256)
      o[c] = 0.5f*((float)n0[c] + (float)n1[c]);
  }
}

extern "C" void kernel_launch(void* const* d_in, const int* in_sizes, int n_in,
                              void* d_out, int out_size, void* d_ws, size_t ws_size,
                              hipStream_t stream) {
  const float* x     = (const float*)d_in[0];
  const float* feat  = (const float*)d_in[1];
  const float* Wphi  = (const float*)d_in[2];
  const float* bphi  = (const float*)d_in[3];
  const float* Wpsi  = (const float*)d_in[4];
  const float* bpsi  = (const float*)d_in[5];
  const float* Wnode = (const float*)d_in[6];
  const float* bnode = (const float*)d_in[7];
  const float* Wrel  = (const float*)d_in[8];
  const float* brel  = (const float*)d_in[9];
  const int*   pairs = (const int*)d_in[10];
  float* out = (float*)d_out;
  char* ws = (char*)d_ws;

  h16*   W3t   = (h16*)(ws + O_W3T);
  h16*   Wrelt = (h16*)(ws + O_WREL);
  h16*   xh    = (h16*)(ws + O_XH);
  h16*   G     = (h16*)(ws + O_G);
  float* b3    = (float*)(ws + O_B3);
  h16*   Yh    = (h16*)(ws + O_YH);

  k_prep<<<dim3(5126), dim3(256), 0, stream>>>(
      Wphi, Wpsi, Wnode, Wrel, x, bphi, bpsi, bnode, feat, pairs,
      W3t, Wrelt, xh, b3, G);
  k_gemm<<<dim3(256), dim3(512), 0, stream>>>(
      xh, W3t, b3, Yh, G, Wrelt, brel, out);
  k_epilogue<<<dim3(1032), dim3(256), 0, stream>>>(Yh, pairs, out);
}

// Round 16
// 33.790 us; speedup vs baseline: 1.0771x; 1.0771x over previous
//
#include <hip/hip_runtime.h>
#include <hip/hip_bf16.h>

// B=8, N=64, P=128, DNODE=2048, DEDGE=1024, DEMB=512, E=32768
// lookup(b,i,j)=b*4096+i*64+j; only 2048 of 32768 edge rows used; (e1+e2)*0.5
// folds into the gathered GEMM input (linearity).
// Budget: gemm 14us (R13-R14 probe), prep ~6 (BW floor), epi ~5, gaps ~5.
// R15 lesson: global_load_lds w/ vmcnt(2) < reg-staged depth-3 -> reverted.
// This round: 2-way SPLIT-K across waves (0-3: k[0,32), 4-7: k[32,64) of each
// BK=64 chunk), each wave a 32x32 subtile -> LDS reads/MFMA 1.5->1.0; one
// LDS merge per tile. Same structure in epilogue scores (512 thr, S=8).

typedef _Float16 h16;
typedef h16 h16x4 __attribute__((ext_vector_type(4)));
typedef h16 h16x8 __attribute__((ext_vector_type(8)));
typedef float f32x4 __attribute__((ext_vector_type(4)));

// ---------------- ws layout (bytes) ----------------
static const long O_W3T  = 0;         // 1536*2048*2 (phi|psi|node K-major)
static const long O_WREL = 6291456;   // 512*1024*2
static const long O_XH   = 7340032;   // 512*2048*2
static const long O_G    = 9437184;   // 1024*1024*2 (0.5*(f_fwd+f_rev) f16)
static const long O_B3   = 11534336;  // 1536*4
static const long O_YH   = 11540480;  // 512*1536*2 (phi|psi|node f16)

__global__ __launch_bounds__(256) void k_prep(
    const float* __restrict__ Wphi, const float* __restrict__ Wpsi,
    const float* __restrict__ Wnode, const float* __restrict__ Wrel,
    const float* __restrict__ x, const float* __restrict__ bphi,
    const float* __restrict__ bpsi, const float* __restrict__ bnode,
    const float* __restrict__ feat, const int* __restrict__ pairs,
    h16* __restrict__ W3t, h16* __restrict__ Wrelt, h16* __restrict__ xh,
    float* __restrict__ b3, h16* __restrict__ G) {
  __shared__ float t[32][33];
  int bid = blockIdx.x, tid = threadIdx.x;
  if (bid < 3584) {
    const float* src; h16* dst; int K, tk, tn;
    if (bid < 3072) {
      int mat = bid >> 10, rem = bid & 1023;
      tk = rem >> 4; tn = rem & 15;
      src = mat == 0 ? Wphi : (mat == 1 ? Wpsi : Wnode);
      K = 2048; dst = W3t + (long)mat * 512 * 2048;
    } else {
      int rem = bid - 3072;
      tk = rem >> 4; tn = rem & 15;
      src = Wrel; K = 1024; dst = Wrelt;
    }
    {
      int row = tid >> 3, c4 = (tid & 7) * 4;
      float4 v = *(const float4*)(src + (long)(tk*32 + row)*512 + tn*32 + c4);
      t[row][c4+0] = v.x; t[row][c4+1] = v.y; t[row][c4+2] = v.z; t[row][c4+3] = v.w;
    }
    __syncthreads();
    {
      int n = tid >> 3, k4 = (tid & 7) * 4;
      h16x4 o = { (h16)t[k4+0][n], (h16)t[k4+1][n], (h16)t[k4+2][n], (h16)t[k4+3][n] };
      *(h16x4*)(dst + (long)(tn*32 + n)*K + tk*32 + k4) = o;
    }
  } else if (bid < 4102) {
    int b2 = bid - 3584;
    if (b2 < 512) {
      int idx = (b2*256 + tid) * 8;
      const float4* xv = (const float4*)(x + idx);
      float4 v0 = xv[0], v1 = xv[1];
      h16x8 o;
      o[0]=(h16)v0.x; o[1]=(h16)v0.y; o[2]=(h16)v0.z; o[3]=(h16)v0.w;
      o[4]=(h16)v1.x; o[5]=(h16)v1.y; o[6]=(h16)v1.z; o[7]=(h16)v1.w;
      *(h16x8*)(xh + idx) = o;
    } else {
      int i = (b2 - 512)*256 + tid;
      if (i < 1536) b3[i] = i < 512 ? bphi[i] : (i < 1024 ? bpsi[i-512] : bnode[i-1024]);
    }
  } else {
    int r = bid - 4102;
    int b = r >> 7;
    int i0 = pairs[r*2], i1 = pairs[r*2+1];
    const float4* f0 = (const float4*)(feat + (long)((b*64 + i0)*64 + i1) * 1024);
    const float4* f1 = (const float4*)(feat + (long)((b*64 + i1)*64 + i0) * 1024);
    float4 a = f0[tid], c = f1[tid];
    h16x4 o;
    o[0]=(h16)(0.5f*(a.x+c.x)); o[1]=(h16)(0.5f*(a.y+c.y));
    o[2]=(h16)(0.5f*(a.z+c.z)); o[3]=(h16)(0.5f*(a.w+c.w));
    *(h16x4*)(G + (long)r*1024 + tid*4) = o;
  }
}

// 4 reads / 4 MFMA on one 32-wide K-slice (kb = kslice*32 + (lane>>4)*8).
__device__ __forceinline__ void mfma4(
    const h16 (*__restrict__ As)[72], const h16 (*__restrict__ Bs)[72],
    int wm, int wn, int kb, int fr, f32x4 acc[2][2]) {
  h16x8 fa0 = *(const h16x8*)&As[wm*32 + fr][kb];
  h16x8 fa1 = *(const h16x8*)&As[wm*32 + 16 + fr][kb];
  h16x8 fb0 = *(const h16x8*)&Bs[wn*32 + fr][kb];
  h16x8 fb1 = *(const h16x8*)&Bs[wn*32 + 16 + fr][kb];
  acc[0][0] = __builtin_amdgcn_mfma_f32_16x16x32_f16(fa0, fb0, acc[0][0], 0,0,0);
  acc[0][1] = __builtin_amdgcn_mfma_f32_16x16x32_f16(fa0, fb1, acc[0][1], 0,0,0);
  acc[1][0] = __builtin_amdgcn_mfma_f32_16x16x32_f16(fa1, fb0, acc[1][0], 0,0,0);
  acc[1][1] = __builtin_amdgcn_mfma_f32_16x16x32_f16(fa1, fb1, acc[1][1], 0,0,0);
}

// Publish LDS writes, keep global loads in flight (verified R12-R14).
#define BAR_LDS() { asm volatile("s_waitcnt lgkmcnt(0)" ::: "memory"); \
                    __builtin_amdgcn_s_barrier(); }

// Depth-3 reg-prefetch tile loop (R14-verified schedule), split-K compute.
// Agp/Bgp are per-thread pointers (row+chunk already applied); steps = S.
template<int S>
__device__ __forceinline__ void tile_splitk(
    const h16* Agp, const h16* Bgp,
    h16 (*As)[64][72], h16 (*Bs)[64][72],
    int srow, int skp, int wm, int wn, int kb, int fr,
    f32x4 acc[2][2]) {
  h16x8 r0a = *(const h16x8*)(Agp);
  h16x8 r0b = *(const h16x8*)(Bgp);
  *(h16x8*)&As[0][srow][skp] = r0a;
  *(h16x8*)&Bs[0][srow][skp] = r0b;
  h16x8 ra1 = *(const h16x8*)(Agp + 64),  rb1 = *(const h16x8*)(Bgp + 64);
  h16x8 ra2 = *(const h16x8*)(Agp + 128), rb2 = *(const h16x8*)(Bgp + 128);
  BAR_LDS();
  int cur = 0;
#pragma unroll 1
  for (int k0 = 192; k0 < S * 64; k0 += 64) {
    h16x8 raF = *(const h16x8*)(Agp + k0);   // 3 steps ahead
    h16x8 rbF = *(const h16x8*)(Bgp + k0);
    mfma4(As[cur], Bs[cur], wm, wn, kb, fr, acc);
    *(h16x8*)&As[cur ^ 1][srow][skp] = ra1;  // issued 2 iters ago: no stall
    *(h16x8*)&Bs[cur ^ 1][srow][skp] = rb1;
    BAR_LDS();
    ra1 = ra2; rb1 = rb2; ra2 = raF; rb2 = rbF;
    cur ^= 1;
  }
  mfma4(As[cur], Bs[cur], wm, wn, kb, fr, acc);
  *(h16x8*)&As[cur ^ 1][srow][skp] = ra1;
  *(h16x8*)&Bs[cur ^ 1][srow][skp] = rb1;
  BAR_LDS();
  cur ^= 1;
  mfma4(As[cur], Bs[cur], wm, wn, kb, fr, acc);
  *(h16x8*)&As[cur ^ 1][srow][skp] = ra2;
  *(h16x8*)&Bs[cur ^ 1][srow][skp] = rb2;
  BAR_LDS();
  cur ^= 1;
  mfma4(As[cur], Bs[cur], wm, wn, kb, fr, acc);
}

// Merge K-slice partials: waves 4-7 dump acc to LDS, waves 0-3 add.
__device__ __forceinline__ void splitk_merge(
    h16 (*As)[64][72], int wave, int lane, f32x4 acc[2][2]) {
  float* mb = (float*)As;   // 16 KB scratch inside As (18 KB)
  __syncthreads();          // all fragment reads of As done
  if (wave >= 4) {
    int mi = ((wave - 4) * 64 + lane) * 16;
    *(f32x4*)&mb[mi +  0] = acc[0][0];
    *(f32x4*)&mb[mi +  4] = acc[0][1];
    *(f32x4*)&mb[mi +  8] = acc[1][0];
    *(f32x4*)&mb[mi + 12] = acc[1][1];
  }
  __syncthreads();
  if (wave < 4) {
    int mi = (wave * 64 + lane) * 16;
    acc[0][0] += *(const f32x4*)&mb[mi +  0];
    acc[0][1] += *(const f32x4*)&mb[mi +  4];
    acc[1][0] += *(const f32x4*)&mb[mi +  8];
    acc[1][1] += *(const f32x4*)&mb[mi + 12];
  }
}

// 256 blocks x 512 threads. Waves: kslice=wave>>2, (wm,wn)=((wave&3)>>1,wave&1)
// -> 2x2 waves of 32x32 over the 64x64 tile, x2 K-slices.
__global__ __launch_bounds__(512) void k_gemm(
    const h16* __restrict__ xh, const h16* __restrict__ W3t,
    const float* __restrict__ b3, h16* __restrict__ Yh,
    const h16* __restrict__ G, const h16* __restrict__ Wrelt,
    const float* __restrict__ brel, float* __restrict__ out) {
  __shared__ __align__(16) h16 As[2][64][72];
  __shared__ __align__(16) h16 Bs[2][64][72];
  int bid = blockIdx.x, tid = threadIdx.x;
  int lane = tid & 63, wave = tid >> 6;
  int kslice = wave >> 2, wsub = wave & 3;
  int wm = wsub >> 1, wn = wsub & 1;
  int srow = tid >> 3, skp = (tid & 7) * 8;
  int fr = lane & 15, kb = kslice * 32 + (lane >> 4) * 8;
  int r0 = 4 * (lane >> 4), c0 = lane & 15;

  int isEdge = bid >= 192;
  int ntile = isEdge ? 2 : 1;
#pragma unroll 1
  for (int ti = 0; ti < ntile; ++ti) {
    if (ti) __syncthreads();
    const h16 *A, *Bt; int K, tileM, tileN;
    if (!isEdge) {               // Yh(512x1536) = xh @ W3t^T + b3
      A = xh; Bt = W3t; K = 2048;
      tileM = (bid / 24) * 64; tileN = (bid % 24) * 64;
    } else {                     // edge(1024x512) = G @ Wrelt^T + brel
      int e = (bid - 192) * 2 + ti;           // 128 tiles
      A = G; Bt = Wrelt; K = 1024;
      tileM = (e >> 3) * 64; tileN = (e & 7) * 64;
    }
    const h16* Agp = A + (long)(tileM + srow) * K + skp;
    const h16* Bgp = Bt + (long)(tileN + srow) * K + skp;
    f32x4 acc[2][2] = {};
    if (!isEdge) tile_splitk<32>(Agp, Bgp, As, Bs, srow, skp, wm, wn, kb, fr, acc);
    else         tile_splitk<16>(Agp, Bgp, As, Bs, srow, skp, wm, wn, kb, fr, acc);
    splitk_merge(As, wave, lane, acc);

    if (wave < 4) {
#pragma unroll
      for (int m = 0; m < 2; ++m)
#pragma unroll
        for (int n = 0; n < 2; ++n) {
          int row = tileM + wm*32 + m*16 + r0;
          int col = tileN + wn*32 + n*16 + c0;
          if (!isEdge) {
            float bb = b3[col];
#pragma unroll
            for (int r = 0; r < 4; ++r)
              Yh[(long)(row + r) * 1536 + col] = (h16)(acc[m][n][r] + bb);
          } else {
            float bb = brel[col];
#pragma unroll
            for (int r = 0; r < 4; ++r)
              out[32768 + 512 + (long)(row + r) * 1024 + col] = acc[m][n][r] + bb;
          }
        }
    }
  }
}

// blocks 0..7: scores = sigmoid(phi_h @ psi_h^T) (K=512, split-K structure);
// blocks 8..1031: first half from Yh node cols. 512 threads.
__global__ __launch_bounds__(512) void k_epilogue(
    const h16* __restrict__ Yh, const int* __restrict__ pairs,
    float* __restrict__ out) {
  __shared__ __align__(16) h16 As[2][64][72];
  __shared__ __align__(16) h16 Bs[2][64][72];
  int bid = blockIdx.x, tid = threadIdx.x;
  if (bid < 8) {
    int lane = tid & 63, wave = tid >> 6;
    int kslice = wave >> 2, wsub = wave & 3;
    int wm = wsub >> 1, wn = wsub & 1;
    int srow = tid >> 3, skp = (tid & 7) * 8;
    int fr = lane & 15, kb = kslice * 32 + (lane >> 4) * 8;
    const h16* Ab = Yh + (long)bid * 64 * 1536;
    const h16* Agp = Ab + (long)srow * 1536 + skp;         // phi rows
    const h16* Bgp = Ab + (long)srow * 1536 + 512 + skp;   // psi rows
    f32x4 acc[2][2] = {};
    tile_splitk<8>(Agp, Bgp, As, Bs, srow, skp, wm, wn, kb, fr, acc);
    splitk_merge(As, wave, lane, acc);
    if (wave < 4) {
      int r0 = 4 * (lane >> 4), c0 = lane & 15;
      float* ob = out + (long)bid * 4096;
#pragma unroll
      for (int m = 0; m < 2; ++m)
#pragma unroll
        for (int n = 0; n < 2; ++n) {
          int row = wm*32 + m*16 + r0;
          int col = wn*32 + n*16 + c0;
#pragma unroll
          for (int r = 0; r < 4; ++r) {
            float s = acc[m][n][r];
            ob[(long)(row + r) * 64 + col] = 1.f / (1.f + expf(-s));
          }
        }
    }
  } else {
    int r = bid - 8;
    int b = r >> 7;
    int i0 = pairs[r*2], i1 = pairs[r*2+1];
    const h16* n0 = Yh + (long)(b*64 + i0)*1536 + 1024;
    const h16* n1 = Yh + (long)(b*64 + i1)*1536 + 1024;
    float* o = out + 32768 + (long)r*1024;
    if (tid < 512)
      o[tid] = 0.5f*((float)n0[tid] + (float)n1[tid]);
  }
}

extern "C" void kernel_launch(void* const* d_in, const int* in_sizes, int n_in,
                              void* d_out, int out_size, void* d_ws, size_t ws_size,
                              hipStream_t stream) {
  const float* x     = (const float*)d_in[0];
  const float* feat  = (const float*)d_in[1];
  const float* Wphi  = (const float*)d_in[2];
  const float* bphi  = (const float*)d_in[3];
  const float* Wpsi  = (const float*)d_in[4];
  const float* bpsi  = (const float*)d_in[5];
  const float* Wnode = (const float*)d_in[6];
  const float* bnode = (const float*)d_in[7];
  const float* Wrel  = (const float*)d_in[8];
  const float* brel  = (const float*)d_in[9];
  const int*   pairs = (const int*)d_in[10];
  float* out = (float*)d_out;
  char* ws = (char*)d_ws;

  h16*   W3t   = (h16*)(ws + O_W3T);
  h16*   Wrelt = (h16*)(ws + O_WREL);
  h16*   xh    = (h16*)(ws + O_XH);
  h16*   G     = (h16*)(ws + O_G);
  float* b3    = (float*)(ws + O_B3);
  h16*   Yh    = (h16*)(ws + O_YH);

  k_prep<<<dim3(5126), dim3(256), 0, stream>>>(
      Wphi, Wpsi, Wnode, Wrel, x, bphi, bpsi, bnode, feat, pairs,
      W3t, Wrelt, xh, b3, G);
  k_gemm<<<dim3(256), dim3(512), 0, stream>>>(
      xh, W3t, b3, Yh, G, Wrelt, brel, out);
  k_epilogue<<<dim3(1032), dim3(512), 0, stream>>>(Yh, pairs, out);
}